// Round 1
// baseline (159.571 us; speedup 1.0000x reference)
//
#include <hip/hip_runtime.h>
#include <math.h>

#define BATCH   64
#define NFEAT   256
#define GS      4
#define NG      64
#define WH      3136            // 56*56
#define PLANEQ  784             // WH/4 (float4 quads per channel plane)
#define NTOT    (BATCH*WH)      // 200704 samples per channel
#define EPSV    1e-3

// ---------------- Stage 1: per-(b,g) partial sums ----------------
// For each block (b, g): partial sums over 3136 spatial positions of
//   s_i   = sum x_i              (4 values)
//   p_ij  = sum x_i * x_j, i<=j  (10 values)
// Written to partials[(g*64 + b)*14 + q]  (deterministic, no atomics).
__global__ __launch_bounds__(256) void wh_reduce(const float* __restrict__ x,
                                                 float* __restrict__ partials) {
    const int blk = blockIdx.x;
    const int b = blk >> 6;
    const int g = blk & 63;
    const float4* __restrict__ xin =
        (const float4*)(x + (size_t)b * ((size_t)NFEAT * WH) + (size_t)g * (GS * WH));

    float s0=0.f,s1=0.f,s2=0.f,s3=0.f;
    float p0=0.f,p1=0.f,p2=0.f,p3=0.f,p4=0.f,p5=0.f,p6=0.f,p7=0.f,p8=0.f,p9=0.f;

    for (int q = threadIdx.x; q < PLANEQ; q += 256) {
        float4 v0 = xin[q];
        float4 v1 = xin[q + PLANEQ];
        float4 v2 = xin[q + 2*PLANEQ];
        float4 v3 = xin[q + 3*PLANEQ];
        float a[4]  = {v0.x, v0.y, v0.z, v0.w};
        float bb[4] = {v1.x, v1.y, v1.z, v1.w};
        float c[4]  = {v2.x, v2.y, v2.z, v2.w};
        float d[4]  = {v3.x, v3.y, v3.z, v3.w};
        #pragma unroll
        for (int k = 0; k < 4; ++k) {
            s0 += a[k]; s1 += bb[k]; s2 += c[k]; s3 += d[k];
            p0 = fmaf(a[k],  a[k],  p0);
            p1 = fmaf(a[k],  bb[k], p1);
            p2 = fmaf(a[k],  c[k],  p2);
            p3 = fmaf(a[k],  d[k],  p3);
            p4 = fmaf(bb[k], bb[k], p4);
            p5 = fmaf(bb[k], c[k],  p5);
            p6 = fmaf(bb[k], d[k],  p6);
            p7 = fmaf(c[k],  c[k],  p7);
            p8 = fmaf(c[k],  d[k],  p8);
            p9 = fmaf(d[k],  d[k],  p9);
        }
    }

    float vals[14] = {s0,s1,s2,s3,p0,p1,p2,p3,p4,p5,p6,p7,p8,p9};
    #pragma unroll
    for (int q = 0; q < 14; ++q) {
        float v = vals[q];
        #pragma unroll
        for (int off = 32; off > 0; off >>= 1) v += __shfl_down(v, off, 64);
        vals[q] = v;
    }

    __shared__ float lds[4][14];
    const int wave = threadIdx.x >> 6;
    const int lane = threadIdx.x & 63;
    if (lane == 0) {
        #pragma unroll
        for (int q = 0; q < 14; ++q) lds[wave][q] = vals[q];
    }
    __syncthreads();
    if (threadIdx.x < 14) {
        float v = lds[0][threadIdx.x] + lds[1][threadIdx.x]
                + lds[2][threadIdx.x] + lds[3][threadIdx.x];
        partials[((size_t)(g * BATCH + b)) * 14 + threadIdx.x] = v;
    }
}

// ---------------- Stage 2: per-group eigen solve (64 threads, 1 block) ----
// Sums the 64 per-batch partials (double), builds the shrunk covariance,
// runs cyclic Jacobi (fully unrolled -> registers), writes per group:
//   wm[g*20 + 0..15]  = W = U diag(1/sqrt(s+eps)) U^T
//   wm[g*20 + 16..19] = channel means m
__global__ __launch_bounds__(64) void wh_eigen(const float* __restrict__ partials,
                                               float* __restrict__ wm) {
    const int g = threadIdx.x;
    if (g >= NG) return;

    double acc[14];
    #pragma unroll
    for (int q = 0; q < 14; ++q) acc[q] = 0.0;
    const float* base = partials + (size_t)g * BATCH * 14;
    for (int b = 0; b < BATCH; ++b) {
        #pragma unroll
        for (int q = 0; q < 14; ++q) acc[q] += (double)base[b * 14 + q];
    }

    const double n = (double)NTOT;
    double m[4];
    #pragma unroll
    for (int i = 0; i < 4; ++i) m[i] = acc[i] / n;

    // pair ordering of the 10 products
    const int pi[10] = {0,0,0,0,1,1,1,2,2,3};
    const int pj[10] = {0,1,2,3,1,2,3,2,3,3};

    double A[4][4];
    #pragma unroll
    for (int t = 0; t < 10; ++t) {
        double cov = acc[4 + t] - n * m[pi[t]] * m[pj[t]];
        double v = (1.0 - EPSV) * cov + ((pi[t] == pj[t]) ? EPSV : 0.0);
        A[pi[t]][pj[t]] = v;
        A[pj[t]][pi[t]] = v;
    }

    double V[4][4] = {{1,0,0,0},{0,1,0,0},{0,0,1,0},{0,0,0,1}};

    #pragma unroll
    for (int sweep = 0; sweep < 12; ++sweep) {
        #pragma unroll
        for (int t = 0; t < 10; ++t) {
            const int p = pi[t], q = pj[t];
            if (p == q) continue;
            double apq = A[p][q];
            if (fabs(apq) < 1e-300) continue;
            double theta = (A[q][q] - A[p][p]) / (2.0 * apq);
            double tt = ((theta >= 0.0) ? 1.0 : -1.0) /
                        (fabs(theta) + sqrt(theta * theta + 1.0));
            double c = 1.0 / sqrt(tt * tt + 1.0);
            double s = tt * c;
            #pragma unroll
            for (int k = 0; k < 4; ++k) {
                double akp = A[k][p], akq = A[k][q];
                A[k][p] = c * akp - s * akq;
                A[k][q] = s * akp + c * akq;
            }
            #pragma unroll
            for (int k = 0; k < 4; ++k) {
                double apk = A[p][k], aqk = A[q][k];
                A[p][k] = c * apk - s * aqk;
                A[q][k] = s * apk + c * aqk;
            }
            #pragma unroll
            for (int k = 0; k < 4; ++k) {
                double vkp = V[k][p], vkq = V[k][q];
                V[k][p] = c * vkp - s * vkq;
                V[k][q] = s * vkp + c * vkq;
            }
        }
    }

    double isq[4];
    #pragma unroll
    for (int k = 0; k < 4; ++k) isq[k] = 1.0 / sqrt(A[k][k] + EPSV);

    float* wo = wm + g * 20;
    #pragma unroll
    for (int i = 0; i < 4; ++i) {
        #pragma unroll
        for (int j = 0; j < 4; ++j) {
            double w = 0.0;
            #pragma unroll
            for (int k = 0; k < 4; ++k) w += V[i][k] * V[j][k] * isq[k];
            wo[i * 4 + j] = (float)w;
        }
    }
    #pragma unroll
    for (int i = 0; i < 4; ++i) wo[16 + i] = (float)m[i];
}

// ---------------- Stage 3: apply out = W (x - m) ----------------
__global__ __launch_bounds__(256) void wh_apply(const float* __restrict__ x,
                                                const float* __restrict__ wm,
                                                float* __restrict__ out) {
    const int blk = blockIdx.x;
    const int b = blk >> 6;
    const int g = blk & 63;

    __shared__ float sW[20];
    if (threadIdx.x < 20) sW[threadIdx.x] = wm[g * 20 + threadIdx.x];
    __syncthreads();

    float W[4][4], mm[4];
    #pragma unroll
    for (int i = 0; i < 4; ++i) {
        #pragma unroll
        for (int j = 0; j < 4; ++j) W[i][j] = sW[i * 4 + j];
        mm[i] = sW[16 + i];
    }

    const size_t off = (size_t)b * ((size_t)NFEAT * WH) + (size_t)g * (GS * WH);
    const float4* __restrict__ xin = (const float4*)(x + off);
    float4* __restrict__ o = (float4*)(out + off);

    for (int q = threadIdx.x; q < PLANEQ; q += 256) {
        float4 v[4];
        v[0] = xin[q];
        v[1] = xin[q + PLANEQ];
        v[2] = xin[q + 2 * PLANEQ];
        v[3] = xin[q + 3 * PLANEQ];

        float c[4][4];
        #pragma unroll
        for (int j = 0; j < 4; ++j) {
            c[j][0] = v[j].x - mm[j];
            c[j][1] = v[j].y - mm[j];
            c[j][2] = v[j].z - mm[j];
            c[j][3] = v[j].w - mm[j];
        }

        #pragma unroll
        for (int i = 0; i < 4; ++i) {
            float4 r;
            r.x = fmaf(W[i][0], c[0][0], fmaf(W[i][1], c[1][0], fmaf(W[i][2], c[2][0], W[i][3] * c[3][0])));
            r.y = fmaf(W[i][0], c[0][1], fmaf(W[i][1], c[1][1], fmaf(W[i][2], c[2][1], W[i][3] * c[3][1])));
            r.z = fmaf(W[i][0], c[0][2], fmaf(W[i][1], c[1][2], fmaf(W[i][2], c[2][2], W[i][3] * c[3][2])));
            r.w = fmaf(W[i][0], c[0][3], fmaf(W[i][1], c[1][3], fmaf(W[i][2], c[2][3], W[i][3] * c[3][3])));
            o[q + i * PLANEQ] = r;
        }
    }
}

extern "C" void kernel_launch(void* const* d_in, const int* in_sizes, int n_in,
                              void* d_out, int out_size, void* d_ws, size_t ws_size,
                              hipStream_t stream) {
    const float* x = (const float*)d_in[0];
    float* out = (float*)d_out;

    float* partials = (float*)d_ws;                 // 64*64*14 floats = 224 KiB
    float* wm       = partials + (size_t)NG * BATCH * 14;  // 64*20 floats

    wh_reduce<<<BATCH * NG, 256, 0, stream>>>(x, partials);
    wh_eigen<<<1, 64, 0, stream>>>(partials, wm);
    wh_apply<<<BATCH * NG, 256, 0, stream>>>(x, wm, out);
}

// Round 3
// 110.223 us; speedup vs baseline: 1.4477x; 1.4477x over previous
//
#include <hip/hip_runtime.h>
#include <math.h>

#define BATCH   64
#define NFEAT   256
#define GS      4
#define NG      64
#define WH      3136            // 56*56
#define PLANEQ  784             // WH/4 (float4 quads per channel plane)
#define NTOT    (BATCH*WH)      // 200704 samples per channel
#define EPSV    1e-3

typedef float vf4 __attribute__((ext_vector_type(4)));

// ---------------- Stage 1: per-(b,g) partial sums ----------------
// For each block (b, g): partial sums over 3136 spatial positions of
//   s_i   = sum x_i              (4 values)
//   p_ij  = sum x_i * x_j, i<=j  (10 values)
// Written to partials[(g*64 + b)*14 + q]  (deterministic, no atomics).
__global__ __launch_bounds__(256) void wh_reduce(const float* __restrict__ x,
                                                 float* __restrict__ partials) {
    const int blk = blockIdx.x;
    const int b = blk >> 6;
    const int g = blk & 63;
    const vf4* __restrict__ xin =
        (const vf4*)(x + (size_t)b * ((size_t)NFEAT * WH) + (size_t)g * (GS * WH));

    float s0=0.f,s1=0.f,s2=0.f,s3=0.f;
    float p0=0.f,p1=0.f,p2=0.f,p3=0.f,p4=0.f,p5=0.f,p6=0.f,p7=0.f,p8=0.f,p9=0.f;

    for (int q = threadIdx.x; q < PLANEQ; q += 256) {
        vf4 v0 = xin[q];
        vf4 v1 = xin[q + PLANEQ];
        vf4 v2 = xin[q + 2*PLANEQ];
        vf4 v3 = xin[q + 3*PLANEQ];
        #pragma unroll
        for (int k = 0; k < 4; ++k) {
            float a = v0[k], bb = v1[k], c = v2[k], d = v3[k];
            s0 += a; s1 += bb; s2 += c; s3 += d;
            p0 = fmaf(a,  a,  p0);
            p1 = fmaf(a,  bb, p1);
            p2 = fmaf(a,  c,  p2);
            p3 = fmaf(a,  d,  p3);
            p4 = fmaf(bb, bb, p4);
            p5 = fmaf(bb, c,  p5);
            p6 = fmaf(bb, d,  p6);
            p7 = fmaf(c,  c,  p7);
            p8 = fmaf(c,  d,  p8);
            p9 = fmaf(d,  d,  p9);
        }
    }

    float vals[14] = {s0,s1,s2,s3,p0,p1,p2,p3,p4,p5,p6,p7,p8,p9};
    #pragma unroll
    for (int q = 0; q < 14; ++q) {
        float v = vals[q];
        #pragma unroll
        for (int off = 32; off > 0; off >>= 1) v += __shfl_down(v, off, 64);
        vals[q] = v;
    }

    __shared__ float lds[4][14];
    const int wave = threadIdx.x >> 6;
    const int lane = threadIdx.x & 63;
    if (lane == 0) {
        #pragma unroll
        for (int q = 0; q < 14; ++q) lds[wave][q] = vals[q];
    }
    __syncthreads();
    if (threadIdx.x < 14) {
        float v = lds[0][threadIdx.x] + lds[1][threadIdx.x]
                + lds[2][threadIdx.x] + lds[3][threadIdx.x];
        partials[((size_t)(g * BATCH + b)) * 14 + threadIdx.x] = v;
    }
}

// ---------------- Stage 2: per-group eigen solve ----------------
// One block per group, 64 threads. Lane b loads the 14 partials of (g,b),
// butterfly-reduces across the wave in double, then lane 0 runs a
// tolerance-early-exit cyclic Jacobi (6 off-diag pairs) and writes:
//   wm[g*20 + 0..15]  = W = U diag(1/sqrt(s+eps)) U^T
//   wm[g*20 + 16..19] = channel means m
__global__ __launch_bounds__(64) void wh_eigen(const float* __restrict__ partials,
                                               float* __restrict__ wm) {
    const int g = blockIdx.x;
    const int b = threadIdx.x;      // 0..63 = batch index

    const float* base = partials + ((size_t)(g * BATCH + b)) * 14;
    double acc[14];
    #pragma unroll
    for (int q = 0; q < 14; ++q) acc[q] = (double)base[q];

    #pragma unroll
    for (int off = 32; off > 0; off >>= 1) {
        #pragma unroll
        for (int q = 0; q < 14; ++q) acc[q] += __shfl_xor(acc[q], off, 64);
    }

    if (b != 0) return;

    const double n = (double)NTOT;
    double m[4];
    #pragma unroll
    for (int i = 0; i < 4; ++i) m[i] = acc[i] / n;

    const int pi[10] = {0,0,0,0,1,1,1,2,2,3};
    const int pj[10] = {0,1,2,3,1,2,3,2,3,3};

    double A[4][4];
    #pragma unroll
    for (int t = 0; t < 10; ++t) {
        double cov = acc[4 + t] - n * m[pi[t]] * m[pj[t]];
        double v = (1.0 - EPSV) * cov + ((pi[t] == pj[t]) ? EPSV : 0.0);
        A[pi[t]][pj[t]] = v;
        A[pj[t]][pi[t]] = v;
    }

    double V[4][4] = {{1,0,0,0},{0,1,0,0},{0,0,1,0},{0,0,0,1}};

    const double tr = A[0][0] + A[1][1] + A[2][2] + A[3][3];
    const double tol = 1e-26 * tr * tr + 1e-300;

    const int rp[6] = {0,0,0,1,1,2};
    const int rq[6] = {1,2,3,2,3,3};

    for (int sweep = 0; sweep < 10; ++sweep) {
        double off = 0.0;
        #pragma unroll
        for (int t = 0; t < 6; ++t) off += A[rp[t]][rq[t]] * A[rp[t]][rq[t]];
        if (off < tol) break;

        #pragma unroll
        for (int t = 0; t < 6; ++t) {
            const int p = rp[t], q = rq[t];
            double apq = A[p][q];
            if (apq * apq < 1e-60) continue;
            double theta = (A[q][q] - A[p][p]) / (2.0 * apq);
            double tt = ((theta >= 0.0) ? 1.0 : -1.0) /
                        (fabs(theta) + sqrt(theta * theta + 1.0));
            double c = 1.0 / sqrt(tt * tt + 1.0);
            double s = tt * c;
            #pragma unroll
            for (int k = 0; k < 4; ++k) {
                double akp = A[k][p], akq = A[k][q];
                A[k][p] = c * akp - s * akq;
                A[k][q] = s * akp + c * akq;
            }
            #pragma unroll
            for (int k = 0; k < 4; ++k) {
                double apk = A[p][k], aqk = A[q][k];
                A[p][k] = c * apk - s * aqk;
                A[q][k] = s * apk + c * aqk;
            }
            #pragma unroll
            for (int k = 0; k < 4; ++k) {
                double vkp = V[k][p], vkq = V[k][q];
                V[k][p] = c * vkp - s * vkq;
                V[k][q] = s * vkp + c * vkq;
            }
        }
    }

    double isq[4];
    #pragma unroll
    for (int k = 0; k < 4; ++k) isq[k] = 1.0 / sqrt(A[k][k] + EPSV);

    float* wo = wm + g * 20;
    #pragma unroll
    for (int i = 0; i < 4; ++i) {
        #pragma unroll
        for (int j = 0; j < 4; ++j) {
            double w = 0.0;
            #pragma unroll
            for (int k = 0; k < 4; ++k) w += V[i][k] * V[j][k] * isq[k];
            wo[i * 4 + j] = (float)w;
        }
    }
    #pragma unroll
    for (int i = 0; i < 4; ++i) wo[16 + i] = (float)m[i];
}

// ---------------- Stage 3: apply out = W (x - m) ----------------
// Nontemporal stores: out is never re-read; keep x resident in L3 so this
// pass's read (and the next replay's reduce read) hit Infinity Cache.
__global__ __launch_bounds__(256) void wh_apply(const float* __restrict__ x,
                                                const float* __restrict__ wm,
                                                float* __restrict__ out) {
    const int blk = blockIdx.x;
    const int b = blk >> 6;
    const int g = blk & 63;

    __shared__ float sW[20];
    if (threadIdx.x < 20) sW[threadIdx.x] = wm[g * 20 + threadIdx.x];
    __syncthreads();

    float W[4][4], mm[4];
    #pragma unroll
    for (int i = 0; i < 4; ++i) {
        #pragma unroll
        for (int j = 0; j < 4; ++j) W[i][j] = sW[i * 4 + j];
        mm[i] = sW[16 + i];
    }

    const size_t off = (size_t)b * ((size_t)NFEAT * WH) + (size_t)g * (GS * WH);
    const vf4* __restrict__ xin = (const vf4*)(x + off);
    vf4* __restrict__ o = (vf4*)(out + off);

    for (int q = threadIdx.x; q < PLANEQ; q += 256) {
        vf4 v[4];
        v[0] = xin[q];
        v[1] = xin[q + PLANEQ];
        v[2] = xin[q + 2 * PLANEQ];
        v[3] = xin[q + 3 * PLANEQ];

        float c[4][4];
        #pragma unroll
        for (int j = 0; j < 4; ++j) {
            #pragma unroll
            for (int k = 0; k < 4; ++k) c[j][k] = v[j][k] - mm[j];
        }

        #pragma unroll
        for (int i = 0; i < 4; ++i) {
            vf4 r;
            #pragma unroll
            for (int k = 0; k < 4; ++k) {
                r[k] = fmaf(W[i][0], c[0][k],
                       fmaf(W[i][1], c[1][k],
                       fmaf(W[i][2], c[2][k], W[i][3] * c[3][k])));
            }
            __builtin_nontemporal_store(r, &o[q + i * PLANEQ]);
        }
    }
}

extern "C" void kernel_launch(void* const* d_in, const int* in_sizes, int n_in,
                              void* d_out, int out_size, void* d_ws, size_t ws_size,
                              hipStream_t stream) {
    const float* x = (const float*)d_in[0];
    float* out = (float*)d_out;

    float* partials = (float*)d_ws;                 // 64*64*14 floats = 224 KiB
    float* wm       = partials + (size_t)NG * BATCH * 14;  // 64*20 floats

    wh_reduce<<<BATCH * NG, 256, 0, stream>>>(x, partials);
    wh_eigen<<<NG, 64, 0, stream>>>(partials, wm);
    wh_apply<<<BATCH * NG, 256, 0, stream>>>(x, wm, out);
}